// Round 1
// baseline (5189.525 us; speedup 1.0000x reference)
//
#include <hip/hip_runtime.h>
#include <hip/hip_bf16.h>

// Problem dims (fixed)
#define Bdim 16
#define Sdim 512
#define Ddim 512
#define Hdim 8
#define DKdim 64
#define Fdim 2048
#define Mrows (Bdim * Sdim)   // 8192

// ---------------------------------------------------------------------------
// fp32 tiled GEMM: C[M,N] = A[M,K] @ W[K,N] + bias[N] (+ R[M,N]) (opt relu)
// 64x64 tile, 256 threads, 4x4 micro-tile per thread, K-tile 16.
// ---------------------------------------------------------------------------
__global__ __launch_bounds__(256) void gemm64(
    const float* __restrict__ A, const float* __restrict__ W,
    const float* __restrict__ bias, const float* __restrict__ R,
    float* __restrict__ C, int M, int N, int K, int do_relu)
{
    __shared__ float As[16][65];   // [k][m], padded to break bank conflicts
    __shared__ float Bs[16][64];   // [k][n]

    const int tid = threadIdx.x;
    const int bm = blockIdx.y * 64;
    const int bn = blockIdx.x * 64;
    const int tm = (tid >> 4) * 4;   // 0..60
    const int tn = (tid & 15) * 4;   // 0..60

    // A-tile load mapping: row lm (0..63), 4 consecutive k at lk
    const int lm = tid >> 2;
    const int lk = (tid & 3) * 4;
    // B-tile load mapping: row kb (0..15), 4 consecutive n at nb
    const int kb = tid >> 4;
    const int nb = (tid & 15) * 4;

    float acc[4][4];
#pragma unroll
    for (int i = 0; i < 4; ++i)
#pragma unroll
        for (int j = 0; j < 4; ++j) acc[i][j] = 0.f;

    for (int k0 = 0; k0 < K; k0 += 16) {
        float4 av = *(const float4*)(A + (size_t)(bm + lm) * K + k0 + lk);
        float4 bv = *(const float4*)(W + (size_t)(k0 + kb) * N + bn + nb);
        As[lk + 0][lm] = av.x;
        As[lk + 1][lm] = av.y;
        As[lk + 2][lm] = av.z;
        As[lk + 3][lm] = av.w;
        *(float4*)(&Bs[kb][nb]) = bv;
        __syncthreads();
#pragma unroll
        for (int kk = 0; kk < 16; ++kk) {
            float a0 = As[kk][tm + 0], a1 = As[kk][tm + 1];
            float a2 = As[kk][tm + 2], a3 = As[kk][tm + 3];
            float b0 = Bs[kk][tn + 0], b1 = Bs[kk][tn + 1];
            float b2 = Bs[kk][tn + 2], b3 = Bs[kk][tn + 3];
            acc[0][0] += a0 * b0; acc[0][1] += a0 * b1; acc[0][2] += a0 * b2; acc[0][3] += a0 * b3;
            acc[1][0] += a1 * b0; acc[1][1] += a1 * b1; acc[1][2] += a1 * b2; acc[1][3] += a1 * b3;
            acc[2][0] += a2 * b0; acc[2][1] += a2 * b1; acc[2][2] += a2 * b2; acc[2][3] += a2 * b3;
            acc[3][0] += a3 * b0; acc[3][1] += a3 * b1; acc[3][2] += a3 * b2; acc[3][3] += a3 * b3;
        }
        __syncthreads();
    }

    float4 bv4 = *(const float4*)(bias + bn + tn);
#pragma unroll
    for (int i = 0; i < 4; ++i) {
        const size_t row = (size_t)(bm + tm + i);
        float4 v;
        v.x = acc[i][0] + bv4.x;
        v.y = acc[i][1] + bv4.y;
        v.z = acc[i][2] + bv4.z;
        v.w = acc[i][3] + bv4.w;
        if (R) {
            float4 r4 = *(const float4*)(R + row * N + bn + tn);
            v.x += r4.x; v.y += r4.y; v.z += r4.z; v.w += r4.w;
        }
        if (do_relu) {
            v.x = fmaxf(v.x, 0.f); v.y = fmaxf(v.y, 0.f);
            v.z = fmaxf(v.z, 0.f); v.w = fmaxf(v.w, 0.f);
        }
        *(float4*)(C + row * N + bn + tn) = v;
    }
}

// ---------------------------------------------------------------------------
// Monotonic attention: one block (512 threads) per (b, h, query-row i).
// Q == K (kq_same + query==key in every block of this model).
// K/V layout: [B, S, D] with head slice at column h*64.
// ---------------------------------------------------------------------------
__global__ __launch_bounds__(512) void attn_kernel(
    const float* __restrict__ Kb, const float* __restrict__ Vb,
    const float* __restrict__ gam, float* __restrict__ O, int mask_type)
{
    const int i = blockIdx.x;
    const int h = blockIdx.y;
    const int b = blockIdx.z;
    const int t = threadIdx.x;   // j index, 0..511

    __shared__ float q[DKdim];
    __shared__ float red[Sdim];
    __shared__ float scan[Sdim];
    __shared__ float attn[Sdim];

    const float* Kbase = Kb + (size_t)b * Sdim * Ddim + h * DKdim;
    if (t < DKdim) q[t] = Kbase[(size_t)i * Ddim + t];
    __syncthreads();

    // scores[i][t] = dot(q_i, k_t) / 8
    const float* krow = Kbase + (size_t)t * Ddim;
    float s = 0.f;
#pragma unroll
    for (int d = 0; d < DKdim; ++d) s += q[d] * krow[d];
    s *= 0.125f;

    const bool valid = mask_type ? (t <= i) : (t < i);
    float sm = valid ? s : -1e32f;

    // softmax pass 1 (distance-decay weights)
    red[t] = sm; __syncthreads();
    for (int off = 256; off; off >>= 1) { if (t < off) red[t] = fmaxf(red[t], red[t + off]); __syncthreads(); }
    float m1 = red[0]; __syncthreads();
    float e1 = expf(sm - m1);
    red[t] = e1; __syncthreads();
    for (int off = 256; off; off >>= 1) { if (t < off) red[t] += red[t + off]; __syncthreads(); }
    float sum1 = red[0]; __syncthreads();
    float p = valid ? (e1 / sum1) : 0.f;

    // inclusive cumsum over j (Hillis-Steele)
    scan[t] = p; __syncthreads();
    for (int off = 1; off < Sdim; off <<= 1) {
        float tv = (t >= off) ? scan[t - off] : 0.f;
        __syncthreads();
        scan[t] += tv;
        __syncthreads();
    }
    float distcum = scan[t];
    float disttot = scan[Sdim - 1];

    float pos = fabsf((float)(i - t));
    float dist = sqrtf(fmaxf((disttot - distcum) * pos, 0.f));
    float g = -log1pf(expf(gam[h]));          // -softplus(gamma)
    float te = expf(dist * g);
    te = fminf(fmaxf(te, 1e-5f), 1e5f);

    // softmax pass 2 (decayed scores)
    float s2 = valid ? s * te : -1e32f;
    red[t] = s2; __syncthreads();
    for (int off = 256; off; off >>= 1) { if (t < off) red[t] = fmaxf(red[t], red[t + off]); __syncthreads(); }
    float m2 = red[0]; __syncthreads();
    float e2 = expf(s2 - m2);
    red[t] = e2; __syncthreads();
    for (int off = 256; off; off >>= 1) { if (t < off) red[t] += red[t + off]; __syncthreads(); }
    float sum2 = red[0]; __syncthreads();
    attn[t] = e2 / sum2;
    __syncthreads();

    // out[i][d] = sum_j attn[j] * V[j][d]; 8 j-chunks x 64 d-lanes
    const float* Vbase = Vb + (size_t)b * Sdim * Ddim + h * DKdim;
    const int d = t & 63;
    const int chunk = t >> 6;
    float partial = 0.f;
    const int j0 = chunk * 64;
#pragma unroll 8
    for (int j = j0; j < j0 + 64; ++j)
        partial += attn[j] * Vbase[(size_t)j * Ddim + d];
    red[t] = partial; __syncthreads();
    if (t < 64) {
        float o = 0.f;
#pragma unroll
        for (int c = 0; c < 8; ++c) o += red[c * 64 + t];
        O[((size_t)b * Sdim + i) * Ddim + h * DKdim + t] = o;
    }
}

// ---------------------------------------------------------------------------
// LayerNorm over last dim (512). One block (256 threads) per row.
// ---------------------------------------------------------------------------
__global__ __launch_bounds__(256) void ln_kernel(
    const float* __restrict__ X, const float* __restrict__ g,
    const float* __restrict__ bta, float* __restrict__ Y)
{
    const int row = blockIdx.x;
    const int t = threadIdx.x;
    __shared__ float r1[256], r2[256];
    const float* x = X + (size_t)row * Ddim;
    float a = x[t], b = x[t + 256];
    r1[t] = a + b;
    r2[t] = a * a + b * b;
    __syncthreads();
    for (int off = 128; off; off >>= 1) {
        if (t < off) { r1[t] += r1[t + off]; r2[t] += r2[t + off]; }
        __syncthreads();
    }
    float mean = r1[0] * (1.f / Ddim);
    float var = r2[0] * (1.f / Ddim) - mean * mean;
    float rs = rsqrtf(var + 1e-5f);
    float* y = Y + (size_t)row * Ddim;
    y[t] = (a - mean) * rs * g[t] + bta[t];
    y[t + 256] = (b - mean) * rs * g[t + 256] + bta[t + 256];
}

// ---------------------------------------------------------------------------
extern "C" void kernel_launch(void* const* d_in, const int* in_sizes, int n_in,
                              void* d_out, int out_size, void* d_ws, size_t ws_size,
                              hipStream_t stream)
{
    const float* x0     = (const float*)d_in[0];   // q_embed_data  [B,S,D]
    const float* y0     = (const float*)d_in[1];   // qa_embed_data [B,S,D]
    const float* Wk     = (const float*)d_in[2];   // [L,D,D]
    const float* bk     = (const float*)d_in[3];   // [L,D]
    const float* Wv     = (const float*)d_in[4];
    const float* bv     = (const float*)d_in[5];
    const float* Wo     = (const float*)d_in[6];
    const float* bo     = (const float*)d_in[7];
    const float* gammas = (const float*)d_in[8];   // [L,H]
    const float* ln1g   = (const float*)d_in[9];
    const float* ln1b   = (const float*)d_in[10];
    const float* W1     = (const float*)d_in[11];  // [L,D,F]
    const float* b1     = (const float*)d_in[12];  // [L,F]
    const float* W2     = (const float*)d_in[13];  // [L,F,D]
    const float* b2     = (const float*)d_in[14];  // [L,D]
    const float* ln2g   = (const float*)d_in[15];
    const float* ln2b   = (const float*)d_in[16];

    const size_t NBSD = (size_t)Bdim * Sdim * Ddim;      // 4,194,304 floats
    float* ws  = (float*)d_ws;
    float* Kbuf = ws;                 // K (= Q) projection
    float* Vbuf = Kbuf + NBSD;
    float* AO   = Vbuf + NBSD;        // attention output
    float* T1   = AO + NBSD;          // pre-LN temp
    float* X1   = T1 + NBSD;          // post-LN1 (ffn input) temp
    float* Ybuf = X1 + NBSD;          // y activations (block 0 out)
    float* Xbuf = Ybuf + NBSD;        // x activations (block 1 out)
    float* Hb   = Xbuf + NBSD;        // FFN hidden [M, F]

    auto run_block = [&](int l, const float* qin, const float* vin,
                         int mask_type, bool ffn, float* out) {
        const float* Wk_l = Wk + (size_t)l * Ddim * Ddim;
        const float* bk_l = bk + (size_t)l * Ddim;
        const float* Wv_l = Wv + (size_t)l * Ddim * Ddim;
        const float* bv_l = bv + (size_t)l * Ddim;
        const float* Wo_l = Wo + (size_t)l * Ddim * Ddim;
        const float* bo_l = bo + (size_t)l * Ddim;

        dim3 gD(Ddim / 64, Mrows / 64);
        // K (= Q) and V projections
        gemm64<<<gD, 256, 0, stream>>>(qin, Wk_l, bk_l, nullptr, Kbuf, Mrows, Ddim, Ddim, 0);
        gemm64<<<gD, 256, 0, stream>>>(vin, Wv_l, bv_l, nullptr, Vbuf, Mrows, Ddim, Ddim, 0);
        // monotonic attention
        attn_kernel<<<dim3(Sdim, Hdim, Bdim), 512, 0, stream>>>(
            Kbuf, Vbuf, gammas + (size_t)l * Hdim, AO, mask_type);
        // O-projection + residual, then LN1
        gemm64<<<gD, 256, 0, stream>>>(AO, Wo_l, bo_l, qin, T1, Mrows, Ddim, Ddim, 0);
        float* x1 = ffn ? X1 : out;
        ln_kernel<<<Mrows, 256, 0, stream>>>(T1, ln1g + (size_t)l * Ddim, ln1b + (size_t)l * Ddim, x1);
        if (ffn) {
            const float* W1_l = W1 + (size_t)l * Ddim * Fdim;
            const float* b1_l = b1 + (size_t)l * Fdim;
            const float* W2_l = W2 + (size_t)l * Fdim * Ddim;
            const float* b2_l = b2 + (size_t)l * Ddim;
            gemm64<<<dim3(Fdim / 64, Mrows / 64), 256, 0, stream>>>(
                x1, W1_l, b1_l, nullptr, Hb, Mrows, Fdim, Ddim, 1);
            gemm64<<<gD, 256, 0, stream>>>(Hb, W2_l, b2_l, x1, T1, Mrows, Ddim, Fdim, 0);
            ln_kernel<<<Mrows, 256, 0, stream>>>(T1, ln2g + (size_t)l * Ddim, ln2b + (size_t)l * Ddim, out);
        }
    };

    // Block 0: knowledge encoder, self-attn on y, mask1 (j<=i), FFN
    run_block(0, y0, y0, 1, true, Ybuf);
    // Block 1: question encoder, self-attn on x, mask1, no FFN
    run_block(1, x0, x0, 1, false, Xbuf);
    // Block 2: knowledge retriever, q/k from x, v from y, mask0 (j<i), FFN
    run_block(2, Xbuf, Ybuf, 0, true, (float*)d_out);
}

// Round 2
// 2230.857 us; speedup vs baseline: 2.3262x; 2.3262x over previous
//
#include <hip/hip_runtime.h>
#include <hip/hip_bf16.h>

// Problem dims (fixed)
#define Bdim 16
#define Sdim 512
#define Ddim 512
#define Hdim 8
#define DKdim 64
#define Fdim 2048
#define Mrows (Bdim * Sdim)   // 8192

// ---------------------------------------------------------------------------
// fp32 tiled GEMM: C[M,N] = A[M,K] @ W[K,N] + bias[N] (+ R[M,N]) (opt relu)
// 64x64 tile, 256 threads, 4x4 micro-tile per thread, K-tile 16.
// ---------------------------------------------------------------------------
__global__ __launch_bounds__(256) void gemm64(
    const float* __restrict__ A, const float* __restrict__ W,
    const float* __restrict__ bias, const float* __restrict__ R,
    float* __restrict__ C, int M, int N, int K, int do_relu)
{
    __shared__ float As[16][65];
    __shared__ float Bs[16][64];

    const int tid = threadIdx.x;
    const int bm = blockIdx.y * 64;
    const int bn = blockIdx.x * 64;
    const int tm = (tid >> 4) * 4;
    const int tn = (tid & 15) * 4;

    const int lm = tid >> 2;
    const int lk = (tid & 3) * 4;
    const int kb = tid >> 4;
    const int nb = (tid & 15) * 4;

    float acc[4][4];
#pragma unroll
    for (int i = 0; i < 4; ++i)
#pragma unroll
        for (int j = 0; j < 4; ++j) acc[i][j] = 0.f;

    for (int k0 = 0; k0 < K; k0 += 16) {
        float4 av = *(const float4*)(A + (size_t)(bm + lm) * K + k0 + lk);
        float4 bv = *(const float4*)(W + (size_t)(k0 + kb) * N + bn + nb);
        As[lk + 0][lm] = av.x;
        As[lk + 1][lm] = av.y;
        As[lk + 2][lm] = av.z;
        As[lk + 3][lm] = av.w;
        *(float4*)(&Bs[kb][nb]) = bv;
        __syncthreads();
#pragma unroll
        for (int kk = 0; kk < 16; ++kk) {
            float a0 = As[kk][tm + 0], a1 = As[kk][tm + 1];
            float a2 = As[kk][tm + 2], a3 = As[kk][tm + 3];
            float b0 = Bs[kk][tn + 0], b1 = Bs[kk][tn + 1];
            float b2 = Bs[kk][tn + 2], b3 = Bs[kk][tn + 3];
            acc[0][0] += a0 * b0; acc[0][1] += a0 * b1; acc[0][2] += a0 * b2; acc[0][3] += a0 * b3;
            acc[1][0] += a1 * b0; acc[1][1] += a1 * b1; acc[1][2] += a1 * b2; acc[1][3] += a1 * b3;
            acc[2][0] += a2 * b0; acc[2][1] += a2 * b1; acc[2][2] += a2 * b2; acc[2][3] += a2 * b3;
            acc[3][0] += a3 * b0; acc[3][1] += a3 * b1; acc[3][2] += a3 * b2; acc[3][3] += a3 * b3;
        }
        __syncthreads();
    }

    float4 bv4 = *(const float4*)(bias + bn + tn);
#pragma unroll
    for (int i = 0; i < 4; ++i) {
        const size_t row = (size_t)(bm + tm + i);
        float4 v;
        v.x = acc[i][0] + bv4.x;
        v.y = acc[i][1] + bv4.y;
        v.z = acc[i][2] + bv4.z;
        v.w = acc[i][3] + bv4.w;
        if (R) {
            float4 r4 = *(const float4*)(R + row * N + bn + tn);
            v.x += r4.x; v.y += r4.y; v.z += r4.z; v.w += r4.w;
        }
        if (do_relu) {
            v.x = fmaxf(v.x, 0.f); v.y = fmaxf(v.y, 0.f);
            v.z = fmaxf(v.z, 0.f); v.w = fmaxf(v.w, 0.f);
        }
        *(float4*)(C + row * N + bn + tn) = v;
    }
}

// ---------------------------------------------------------------------------
// K transpose: Kn[b, s, h*64+d] -> Kt[b, h, d, s]   (per-head d-major)
// grid: (S/64, H, B), 256 threads, 64x64 tile via LDS.
// ---------------------------------------------------------------------------
__global__ __launch_bounds__(256) void ktranspose(
    const float* __restrict__ Kn, float* __restrict__ Kt)
{
    __shared__ float T[64][68];
    const int st = blockIdx.x, h = blockIdx.y, b = blockIdx.z;
    const int t = threadIdx.x;
    const int sl = t >> 4, d4 = (t & 15) << 2;
#pragma unroll
    for (int it = 0; it < 4; ++it) {
        const int ss = st * 64 + sl + it * 16;
        float4 v = *(const float4*)(Kn + ((size_t)(b * Sdim + ss)) * Ddim + h * 64 + d4);
        T[d4 + 0][sl + it * 16] = v.x;
        T[d4 + 1][sl + it * 16] = v.y;
        T[d4 + 2][sl + it * 16] = v.z;
        T[d4 + 3][sl + it * 16] = v.w;
    }
    __syncthreads();
    const int dl = t >> 4, s4 = (t & 15) << 2;
#pragma unroll
    for (int it = 0; it < 4; ++it) {
        const int dd = dl + it * 16;
        float4 v;
        v.x = T[dd][s4 + 0]; v.y = T[dd][s4 + 1];
        v.z = T[dd][s4 + 2]; v.w = T[dd][s4 + 3];
        *(float4*)(Kt + ((size_t)((b * Hdim + h) * DKdim + dd)) * Sdim + st * 64 + s4) = v;
    }
}

// ---------------------------------------------------------------------------
// Fused monotonic attention, 16 query rows per block, one (b,h) per block.
// grid: (S/16, H, B), 256 threads (4 waves).
// Wave qg handles q-rows 4qg..4qg+3; lane jg holds j in {4jg..4jg+3} and
// {256+4jg..+3}. Scores live in registers; softmax/cumsum via shuffles.
// ---------------------------------------------------------------------------
#define ASP 520   // A row stride (floats), mult of 4, non-pow2

__global__ __launch_bounds__(256, 3) void attn_fused(
    const float* __restrict__ Kn, const float* __restrict__ Kt,
    const float* __restrict__ Vn, const float* __restrict__ gam,
    float* __restrict__ O, int mask_type)
{
    const int qt = blockIdx.x, h = blockIdx.y, b = blockIdx.z;
    const int t = threadIdx.x;
    const int lane = t & 63;

    __shared__ float A[16][ASP];   // attention probs [q][j]
    __shared__ float U[4096];      // 16 KB union: Qt[64][20] then PV scratch [4][16][64]

    // ---- stage Q^T into U: Qt[d][qi], stride 20
    {
        const int qi = t >> 4, d4 = (t & 15) << 2;
        float4 qv = *(const float4*)(Kn + ((size_t)(b * Sdim + qt * 16 + qi)) * Ddim + h * 64 + d4);
        U[(d4 + 0) * 20 + qi] = qv.x;
        U[(d4 + 1) * 20 + qi] = qv.y;
        U[(d4 + 2) * 20 + qi] = qv.z;
        U[(d4 + 3) * 20 + qi] = qv.w;
    }
    __syncthreads();

    const int qg = t >> 6;   // wave id: q rows 4qg..4qg+3
    const float* ktp = Kt + ((size_t)(b * Hdim + h)) * DKdim * Sdim + (lane << 2);

    float s[4][8];
#pragma unroll
    for (int a = 0; a < 4; ++a)
#pragma unroll
        for (int e = 0; e < 8; ++e) s[a][e] = 0.f;

#pragma unroll 4
    for (int d = 0; d < 64; ++d) {
        const float4 k0 = *(const float4*)(ktp + (size_t)d * Sdim);
        const float4 k1 = *(const float4*)(ktp + (size_t)d * Sdim + 256);
        const float4 qv = *(const float4*)&U[d * 20 + (qg << 2)];
        const float qq[4] = {qv.x, qv.y, qv.z, qv.w};
        const float kk[8] = {k0.x, k0.y, k0.z, k0.w, k1.x, k1.y, k1.z, k1.w};
#pragma unroll
        for (int a = 0; a < 4; ++a)
#pragma unroll
            for (int e = 0; e < 8; ++e) s[a][e] += qq[a] * kk[e];
    }

    // gamma term (once)
    const float gm = gam[h];
    const float gneg = -log1pf(__expf(gm));   // -softplus(gamma)

    // per-row softmax + cumsum + decay + softmax; rows a = 0..3 of this wave
#pragma unroll 1
    for (int a = 0; a < 4; ++a) {
        const int i_row = qt * 16 + (qg << 2) + a;
        float sm[8], p[8];
        float m1 = -1e32f;
#pragma unroll
        for (int e = 0; e < 8; ++e) {
            s[a][e] *= 0.125f;
            const int j = ((e >> 2) << 8) + (lane << 2) + (e & 3);
            const bool valid = mask_type ? (j <= i_row) : (j < i_row);
            sm[e] = valid ? s[a][e] : -1e32f;
            m1 = fmaxf(m1, sm[e]);
        }
#pragma unroll
        for (int o = 32; o; o >>= 1) m1 = fmaxf(m1, __shfl_xor(m1, o));
        float sum1 = 0.f;
#pragma unroll
        for (int e = 0; e < 8; ++e) { p[e] = __expf(sm[e] - m1); sum1 += p[e]; }
#pragma unroll
        for (int o = 32; o; o >>= 1) sum1 += __shfl_xor(sum1, o);
        const float rs1 = 1.f / sum1;
#pragma unroll
        for (int e = 0; e < 8; ++e) {
            const int j = ((e >> 2) << 8) + (lane << 2) + (e & 3);
            const bool valid = mask_type ? (j <= i_row) : (j < i_row);
            p[e] = valid ? p[e] * rs1 : 0.f;
        }
        // local inclusive cumsum within the two runs of 4
        float c[8];
        c[0] = p[0]; c[1] = c[0] + p[1]; c[2] = c[1] + p[2]; c[3] = c[2] + p[3];
        c[4] = p[4]; c[5] = c[4] + p[5]; c[6] = c[5] + p[6]; c[7] = c[6] + p[7];
        // wave inclusive scans of run totals
        float v0 = c[3];
#pragma unroll
        for (int o = 1; o < 64; o <<= 1) { float u = __shfl_up(v0, o); if (lane >= o) v0 += u; }
        const float T0 = __shfl(v0, 63);
        const float ex0 = v0 - c[3];
        float v1 = c[7];
#pragma unroll
        for (int o = 1; o < 64; o <<= 1) { float u = __shfl_up(v1, o); if (lane >= o) v1 += u; }
        const float T1 = __shfl(v1, 63);
        const float ex1 = v1 - c[7];
        const float disttot = T0 + T1;

        // decay + second softmax
        float s2[8];
        float m2 = -1e32f;
#pragma unroll
        for (int e = 0; e < 8; ++e) {
            const int j = ((e >> 2) << 8) + (lane << 2) + (e & 3);
            const bool valid = mask_type ? (j <= i_row) : (j < i_row);
            const float incl = ((e < 4) ? ex0 : (T0 + ex1)) + c[e];
            const float suffix = disttot - incl;
            const float pos = fabsf((float)(i_row - j));
            const float dist = sqrtf(fmaxf(suffix * pos, 0.f));
            float te = __expf(dist * gneg);
            te = fminf(fmaxf(te, 1e-5f), 1e5f);
            s2[e] = valid ? s[a][e] * te : -1e32f;
            m2 = fmaxf(m2, s2[e]);
        }
#pragma unroll
        for (int o = 32; o; o >>= 1) m2 = fmaxf(m2, __shfl_xor(m2, o));
        float sum2 = 0.f;
#pragma unroll
        for (int e = 0; e < 8; ++e) { s2[e] = __expf(s2[e] - m2); sum2 += s2[e]; }
#pragma unroll
        for (int o = 32; o; o >>= 1) sum2 += __shfl_xor(sum2, o);
        const float rs2 = 1.f / sum2;

        float4 w0, w1;
        w0.x = s2[0] * rs2; w0.y = s2[1] * rs2; w0.z = s2[2] * rs2; w0.w = s2[3] * rs2;
        w1.x = s2[4] * rs2; w1.y = s2[5] * rs2; w1.z = s2[6] * rs2; w1.w = s2[7] * rs2;
        *(float4*)&A[(qg << 2) + a][lane << 2] = w0;
        *(float4*)&A[(qg << 2) + a][256 + (lane << 2)] = w1;
    }
    __syncthreads();

    // ---- PV: thread = (js = wave, qg2, dg); each accumulates 4q x 4d over 128 j
    const int js = t >> 6;
    const int qg2 = (t >> 4) & 3;
    const int dg = t & 15;
    float4 acc[4];
#pragma unroll
    for (int qk = 0; qk < 4; ++qk) acc[qk] = make_float4(0.f, 0.f, 0.f, 0.f);

    const float* vp = Vn + ((size_t)(b * Sdim + js * 128)) * Ddim + h * 64 + (dg << 2);
    for (int jj = 0; jj < 128; jj += 4) {
        float4 aa[4];
#pragma unroll
        for (int qk = 0; qk < 4; ++qk)
            aa[qk] = *(const float4*)&A[(qg2 << 2) + qk][js * 128 + jj];
#pragma unroll
        for (int u = 0; u < 4; ++u) {
            const float4 vv = *(const float4*)(vp + (size_t)(jj + u) * Ddim);
            const float au[4] = {
                u == 0 ? aa[0].x : u == 1 ? aa[0].y : u == 2 ? aa[0].z : aa[0].w,
                u == 0 ? aa[1].x : u == 1 ? aa[1].y : u == 2 ? aa[1].z : aa[1].w,
                u == 0 ? aa[2].x : u == 1 ? aa[2].y : u == 2 ? aa[2].z : aa[2].w,
                u == 0 ? aa[3].x : u == 1 ? aa[3].y : u == 2 ? aa[3].z : aa[3].w };
#pragma unroll
            for (int qk = 0; qk < 4; ++qk) {
                acc[qk].x += au[qk] * vv.x;
                acc[qk].y += au[qk] * vv.y;
                acc[qk].z += au[qk] * vv.z;
                acc[qk].w += au[qk] * vv.w;
            }
        }
    }
    // partials -> scratch (overlaps Qt region; Qt dead since QK phase)
#pragma unroll
    for (int qk = 0; qk < 4; ++qk)
        *(float4*)&U[((js * 16) + (qg2 << 2) + qk) * 64 + (dg << 2)] = acc[qk];
    __syncthreads();

    {
        const int q = t >> 4, d4 = (t & 15) << 2;
        float4 r = make_float4(0.f, 0.f, 0.f, 0.f);
#pragma unroll
        for (int j2 = 0; j2 < 4; ++j2) {
            float4 pv = *(const float4*)&U[(j2 * 16 + q) * 64 + d4];
            r.x += pv.x; r.y += pv.y; r.z += pv.z; r.w += pv.w;
        }
        *(float4*)(O + ((size_t)(b * Sdim + qt * 16 + q)) * Ddim + h * 64 + d4) = r;
    }
}

// ---------------------------------------------------------------------------
// LayerNorm over last dim (512). One block (256 threads) per row.
// ---------------------------------------------------------------------------
__global__ __launch_bounds__(256) void ln_kernel(
    const float* __restrict__ X, const float* __restrict__ g,
    const float* __restrict__ bta, float* __restrict__ Y)
{
    const int row = blockIdx.x;
    const int t = threadIdx.x;
    __shared__ float r1[256], r2[256];
    const float* x = X + (size_t)row * Ddim;
    float a = x[t], b = x[t + 256];
    r1[t] = a + b;
    r2[t] = a * a + b * b;
    __syncthreads();
    for (int off = 128; off; off >>= 1) {
        if (t < off) { r1[t] += r1[t + off]; r2[t] += r2[t + off]; }
        __syncthreads();
    }
    float mean = r1[0] * (1.f / Ddim);
    float var = r2[0] * (1.f / Ddim) - mean * mean;
    float rs = rsqrtf(var + 1e-5f);
    float* y = Y + (size_t)row * Ddim;
    y[t] = (a - mean) * rs * g[t] + bta[t];
    y[t + 256] = (b - mean) * rs * g[t + 256] + bta[t + 256];
}

// ---------------------------------------------------------------------------
extern "C" void kernel_launch(void* const* d_in, const int* in_sizes, int n_in,
                              void* d_out, int out_size, void* d_ws, size_t ws_size,
                              hipStream_t stream)
{
    const float* x0     = (const float*)d_in[0];
    const float* y0     = (const float*)d_in[1];
    const float* Wk     = (const float*)d_in[2];
    const float* bk     = (const float*)d_in[3];
    const float* Wv     = (const float*)d_in[4];
    const float* bv     = (const float*)d_in[5];
    const float* Wo     = (const float*)d_in[6];
    const float* bo     = (const float*)d_in[7];
    const float* gammas = (const float*)d_in[8];
    const float* ln1g   = (const float*)d_in[9];
    const float* ln1b   = (const float*)d_in[10];
    const float* W1     = (const float*)d_in[11];
    const float* b1     = (const float*)d_in[12];
    const float* W2     = (const float*)d_in[13];
    const float* b2     = (const float*)d_in[14];
    const float* ln2g   = (const float*)d_in[15];
    const float* ln2b   = (const float*)d_in[16];

    const size_t NBSD = (size_t)Bdim * Sdim * Ddim;
    float* ws  = (float*)d_ws;
    float* Kbuf = ws;
    float* Vbuf = Kbuf + NBSD;
    float* AO   = Vbuf + NBSD;
    float* T1   = AO + NBSD;
    float* X1   = T1 + NBSD;
    float* Ybuf = X1 + NBSD;
    float* Xbuf = Ybuf + NBSD;
    float* Hb   = Xbuf + NBSD;        // FFN hidden [M, F]; also reused as Kt
    float* Ktb  = Hb;                 // Kt[b][h][d][s] (16 MB) — dead before FFN uses Hb

    auto run_block = [&](int l, const float* qin, const float* vin,
                         int mask_type, bool ffn, float* out) {
        const float* Wk_l = Wk + (size_t)l * Ddim * Ddim;
        const float* bk_l = bk + (size_t)l * Ddim;
        const float* Wv_l = Wv + (size_t)l * Ddim * Ddim;
        const float* bv_l = bv + (size_t)l * Ddim;
        const float* Wo_l = Wo + (size_t)l * Ddim * Ddim;
        const float* bo_l = bo + (size_t)l * Ddim;

        dim3 gD(Ddim / 64, Mrows / 64);
        gemm64<<<gD, 256, 0, stream>>>(qin, Wk_l, bk_l, nullptr, Kbuf, Mrows, Ddim, Ddim, 0);
        gemm64<<<gD, 256, 0, stream>>>(vin, Wv_l, bv_l, nullptr, Vbuf, Mrows, Ddim, Ddim, 0);
        ktranspose<<<dim3(Sdim / 64, Hdim, Bdim), 256, 0, stream>>>(Kbuf, Ktb);
        attn_fused<<<dim3(Sdim / 16, Hdim, Bdim), 256, 0, stream>>>(
            Kbuf, Ktb, Vbuf, gammas + (size_t)l * Hdim, AO, mask_type);
        gemm64<<<gD, 256, 0, stream>>>(AO, Wo_l, bo_l, qin, T1, Mrows, Ddim, Ddim, 0);
        float* x1 = ffn ? X1 : out;
        ln_kernel<<<Mrows, 256, 0, stream>>>(T1, ln1g + (size_t)l * Ddim, ln1b + (size_t)l * Ddim, x1);
        if (ffn) {
            const float* W1_l = W1 + (size_t)l * Ddim * Fdim;
            const float* b1_l = b1 + (size_t)l * Fdim;
            const float* W2_l = W2 + (size_t)l * Fdim * Ddim;
            const float* b2_l = b2 + (size_t)l * Ddim;
            gemm64<<<dim3(Fdim / 64, Mrows / 64), 256, 0, stream>>>(
                x1, W1_l, b1_l, nullptr, Hb, Mrows, Fdim, Ddim, 1);
            gemm64<<<gD, 256, 0, stream>>>(Hb, W2_l, b2_l, x1, T1, Mrows, Ddim, Fdim, 0);
            ln_kernel<<<Mrows, 256, 0, stream>>>(T1, ln2g + (size_t)l * Ddim, ln2b + (size_t)l * Ddim, out);
        }
    };

    run_block(0, y0, y0, 1, true, Ybuf);
    run_block(1, x0, x0, 1, false, Xbuf);
    run_block(2, Xbuf, Ybuf, 0, true, (float*)d_out);
}

// Round 3
// 1163.015 us; speedup vs baseline: 4.4621x; 1.9182x over previous
//
#include <hip/hip_runtime.h>
#include <hip/hip_bf16.h>

// Problem dims (fixed)
#define Bdim 16
#define Sdim 512
#define Ddim 512
#define Hdim 8
#define DKdim 64
#define Fdim 2048
#define Mrows (Bdim * Sdim)   // 8192

typedef __attribute__((ext_vector_type(8))) short  frag16;   // 8 bf16 (4 VGPRs)
typedef __attribute__((ext_vector_type(4))) float  f32x4;    // MFMA acc
typedef __attribute__((ext_vector_type(8))) unsigned short ushort8;

// round-to-nearest-even fp32 -> bf16 (finite data)
__device__ __forceinline__ unsigned short f2b(float x) {
    union { float f; unsigned int u; } v; v.f = x;
    unsigned int r = (v.u + 0x7FFFu + ((v.u >> 16) & 1u)) >> 16;
    return (unsigned short)r;
}

// ---------------------------------------------------------------------------
// bf16 MFMA GEMM (m97 structure): C[M,N] = A[M,K] @ Bt[N,K]^T + bias
// 128x128 tile, BK=32, 256 threads (4 waves), wave = 64x64, 4x4 MFMA tiles.
// Staging via global_load_lds width=16 (lane-ordered, unpadded LDS).
// Epilogue: +bias (+R fp32) (relu); writes fp32 Cf and/or bf16 Cb.
// ---------------------------------------------------------------------------
__global__ __launch_bounds__(256) void gemm_mfma(
    const __hip_bfloat16* __restrict__ A,   // [M,K] bf16
    const __hip_bfloat16* __restrict__ Bt,  // [N,K] bf16 (transposed weights)
    const float* __restrict__ bias,         // [N]
    const float* __restrict__ R,            // [M,N] fp32 residual or null
    float* __restrict__ Cf,                 // [M,N] fp32 out or null
    unsigned short* __restrict__ Cb,        // [M,N] bf16 out or null
    int M, int N, int K, int do_relu)
{
    __shared__ short As[128 * 32];   // [m][k] rows contiguous (64 B)
    __shared__ short Bs[128 * 32];   // [n][k]

    const int t = threadIdx.x;
    const int lane = t & 63;
    const int wave = t >> 6;
    const int bm = blockIdx.y * 128;
    const int bn = blockIdx.x * 128;
    const int wm = (wave >> 1) * 64;
    const int wn = (wave & 1) * 64;

    f32x4 acc[4][4] = {};

    const int lrow = lane >> 2;          // row within 16-row chunk
    const int lcol = (lane & 3) * 8;     // bf16 element col (16 B granules)

    for (int k0 = 0; k0 < K; k0 += 32) {
#pragma unroll
        for (int i = 0; i < 2; ++i) {
            const int chunk = wave * 2 + i;           // 0..7 -> 16 rows each
            const int row = chunk * 16 + lrow;
            const __hip_bfloat16* ga = A + (size_t)(bm + row) * K + k0 + lcol;
            const __hip_bfloat16* gb = Bt + (size_t)(bn + row) * K + k0 + lcol;
            __builtin_amdgcn_global_load_lds(
                (const __attribute__((address_space(1))) unsigned int*)ga,
                (__attribute__((address_space(3))) unsigned int*)(As + chunk * 512),
                16, 0, 0);
            __builtin_amdgcn_global_load_lds(
                (const __attribute__((address_space(1))) unsigned int*)gb,
                (__attribute__((address_space(3))) unsigned int*)(Bs + chunk * 512),
                16, 0, 0);
        }
        __syncthreads();

        const int fr = lane & 15;        // m / n within 16-tile
        const int quad = lane >> 4;      // k-half selector (8 elems)
        frag16 af[4], bfr[4];
#pragma unroll
        for (int i = 0; i < 4; ++i) {
            af[i]  = *(const frag16*)(As + (wm + i * 16 + fr) * 32 + quad * 8);
            bfr[i] = *(const frag16*)(Bs + (wn + i * 16 + fr) * 32 + quad * 8);
        }
#pragma unroll
        for (int mi = 0; mi < 4; ++mi)
#pragma unroll
            for (int ni = 0; ni < 4; ++ni)
                acc[mi][ni] = __builtin_amdgcn_mfma_f32_16x16x32_bf16(
                    af[mi], bfr[ni], acc[mi][ni], 0, 0, 0);
        __syncthreads();
    }

    // epilogue: C[m][n], m = bm+wm+mi*16+quad*4+r, n = bn+wn+ni*16+fr
    const int fr = lane & 15;
    const int quad = lane >> 4;
#pragma unroll
    for (int mi = 0; mi < 4; ++mi) {
#pragma unroll
        for (int r = 0; r < 4; ++r) {
            const int m = bm + wm + mi * 16 + quad * 4 + r;
#pragma unroll
            for (int ni = 0; ni < 4; ++ni) {
                const int n = bn + wn + ni * 16 + fr;
                float v = acc[mi][ni][r] + bias[n];
                if (R) v += R[(size_t)m * N + n];
                if (do_relu) v = fmaxf(v, 0.f);
                if (Cf) Cf[(size_t)m * N + n] = v;
                if (Cb) Cb[(size_t)m * N + n] = f2b(v);
            }
        }
    }
}

// ---------------------------------------------------------------------------
// fp32 -> bf16 convert, 8 elems/thread
// ---------------------------------------------------------------------------
__global__ __launch_bounds__(256) void conv_b(
    const float* __restrict__ X, unsigned short* __restrict__ Y)
{
    const size_t i = ((size_t)blockIdx.x * 256 + threadIdx.x) * 8;
    float4 a = *(const float4*)(X + i);
    float4 b = *(const float4*)(X + i + 4);
    ushort8 o;
    o[0] = f2b(a.x); o[1] = f2b(a.y); o[2] = f2b(a.z); o[3] = f2b(a.w);
    o[4] = f2b(b.x); o[5] = f2b(b.y); o[6] = f2b(b.z); o[7] = f2b(b.w);
    *(ushort8*)(Y + i) = o;
}

// ---------------------------------------------------------------------------
// Weight transpose+convert: W[K,N] fp32 -> Wt[N,K] bf16. 64x64 tiles.
// grid: (N/64, K/64), 256 threads.
// ---------------------------------------------------------------------------
__global__ __launch_bounds__(256) void wtrans(
    const float* __restrict__ W, unsigned short* __restrict__ Wt, int K, int N)
{
    __shared__ float T[64][65];
    const int n0 = blockIdx.x * 64, k0 = blockIdx.y * 64;
    const int t = threadIdx.x;
    const int kl = t >> 4, n4 = (t & 15) << 2;
#pragma unroll
    for (int it = 0; it < 4; ++it) {
        const int k = kl + it * 16;
        float4 v = *(const float4*)(W + (size_t)(k0 + k) * N + n0 + n4);
        T[n4 + 0][k] = v.x; T[n4 + 1][k] = v.y;
        T[n4 + 2][k] = v.z; T[n4 + 3][k] = v.w;
    }
    __syncthreads();
    const int nl = t >> 3, k8 = (t & 7) << 3;
#pragma unroll
    for (int it = 0; it < 2; ++it) {
        const int n = nl + it * 32;
        ushort8 o;
#pragma unroll
        for (int c = 0; c < 8; ++c) o[c] = f2b(T[n][k8 + c]);
        *(ushort8*)(Wt + (size_t)(n0 + n) * K + k0 + k8) = o;
    }
}

// ---------------------------------------------------------------------------
// K transpose (fp32): Kn[b, s, h*64+d] -> Kt[b, h, d, s]
// ---------------------------------------------------------------------------
__global__ __launch_bounds__(256) void ktranspose(
    const float* __restrict__ Kn, float* __restrict__ Kt)
{
    __shared__ float T[64][68];
    const int st = blockIdx.x, h = blockIdx.y, b = blockIdx.z;
    const int t = threadIdx.x;
    const int sl = t >> 4, d4 = (t & 15) << 2;
#pragma unroll
    for (int it = 0; it < 4; ++it) {
        const int ss = st * 64 + sl + it * 16;
        float4 v = *(const float4*)(Kn + ((size_t)(b * Sdim + ss)) * Ddim + h * 64 + d4);
        T[d4 + 0][sl + it * 16] = v.x;
        T[d4 + 1][sl + it * 16] = v.y;
        T[d4 + 2][sl + it * 16] = v.z;
        T[d4 + 3][sl + it * 16] = v.w;
    }
    __syncthreads();
    const int dl = t >> 4, s4 = (t & 15) << 2;
#pragma unroll
    for (int it = 0; it < 4; ++it) {
        const int dd = dl + it * 16;
        float4 v;
        v.x = T[dd][s4 + 0]; v.y = T[dd][s4 + 1];
        v.z = T[dd][s4 + 2]; v.w = T[dd][s4 + 3];
        *(float4*)(Kt + ((size_t)((b * Hdim + h) * DKdim + dd)) * Sdim + st * 64 + s4) = v;
    }
}

// ---------------------------------------------------------------------------
// Fused monotonic attention (unchanged from R2 — verified correct)
// ---------------------------------------------------------------------------
#define ASP 520

__global__ __launch_bounds__(256, 3) void attn_fused(
    const float* __restrict__ Kn, const float* __restrict__ Kt,
    const float* __restrict__ Vn, const float* __restrict__ gam,
    float* __restrict__ O, int mask_type)
{
    const int qt = blockIdx.x, h = blockIdx.y, b = blockIdx.z;
    const int t = threadIdx.x;
    const int lane = t & 63;

    __shared__ float A[16][ASP];
    __shared__ float U[4096];

    {
        const int qi = t >> 4, d4 = (t & 15) << 2;
        float4 qv = *(const float4*)(Kn + ((size_t)(b * Sdim + qt * 16 + qi)) * Ddim + h * 64 + d4);
        U[(d4 + 0) * 20 + qi] = qv.x;
        U[(d4 + 1) * 20 + qi] = qv.y;
        U[(d4 + 2) * 20 + qi] = qv.z;
        U[(d4 + 3) * 20 + qi] = qv.w;
    }
    __syncthreads();

    const int qg = t >> 6;
    const float* ktp = Kt + ((size_t)(b * Hdim + h)) * DKdim * Sdim + (lane << 2);

    float s[4][8];
#pragma unroll
    for (int a = 0; a < 4; ++a)
#pragma unroll
        for (int e = 0; e < 8; ++e) s[a][e] = 0.f;

#pragma unroll 4
    for (int d = 0; d < 64; ++d) {
        const float4 k0 = *(const float4*)(ktp + (size_t)d * Sdim);
        const float4 k1 = *(const float4*)(ktp + (size_t)d * Sdim + 256);
        const float4 qv = *(const float4*)&U[d * 20 + (qg << 2)];
        const float qq[4] = {qv.x, qv.y, qv.z, qv.w};
        const float kk[8] = {k0.x, k0.y, k0.z, k0.w, k1.x, k1.y, k1.z, k1.w};
#pragma unroll
        for (int a = 0; a < 4; ++a)
#pragma unroll
            for (int e = 0; e < 8; ++e) s[a][e] += qq[a] * kk[e];
    }

    const float gm = gam[h];
    const float gneg = -log1pf(__expf(gm));

#pragma unroll 1
    for (int a = 0; a < 4; ++a) {
        const int i_row = qt * 16 + (qg << 2) + a;
        float sm[8], p[8];
        float m1 = -1e32f;
#pragma unroll
        for (int e = 0; e < 8; ++e) {
            s[a][e] *= 0.125f;
            const int j = ((e >> 2) << 8) + (lane << 2) + (e & 3);
            const bool valid = mask_type ? (j <= i_row) : (j < i_row);
            sm[e] = valid ? s[a][e] : -1e32f;
            m1 = fmaxf(m1, sm[e]);
        }
#pragma unroll
        for (int o = 32; o; o >>= 1) m1 = fmaxf(m1, __shfl_xor(m1, o));
        float sum1 = 0.f;
#pragma unroll
        for (int e = 0; e < 8; ++e) { p[e] = __expf(sm[e] - m1); sum1 += p[e]; }
#pragma unroll
        for (int o = 32; o; o >>= 1) sum1 += __shfl_xor(sum1, o);
        const float rs1 = 1.f / sum1;
#pragma unroll
        for (int e = 0; e < 8; ++e) {
            const int j = ((e >> 2) << 8) + (lane << 2) + (e & 3);
            const bool valid = mask_type ? (j <= i_row) : (j < i_row);
            p[e] = valid ? p[e] * rs1 : 0.f;
        }
        float c[8];
        c[0] = p[0]; c[1] = c[0] + p[1]; c[2] = c[1] + p[2]; c[3] = c[2] + p[3];
        c[4] = p[4]; c[5] = c[4] + p[5]; c[6] = c[5] + p[6]; c[7] = c[6] + p[7];
        float v0 = c[3];
#pragma unroll
        for (int o = 1; o < 64; o <<= 1) { float u = __shfl_up(v0, o); if (lane >= o) v0 += u; }
        const float T0 = __shfl(v0, 63);
        const float ex0 = v0 - c[3];
        float v1 = c[7];
#pragma unroll
        for (int o = 1; o < 64; o <<= 1) { float u = __shfl_up(v1, o); if (lane >= o) v1 += u; }
        const float T1 = __shfl(v1, 63);
        const float ex1 = v1 - c[7];
        const float disttot = T0 + T1;

        float s2[8];
        float m2 = -1e32f;
#pragma unroll
        for (int e = 0; e < 8; ++e) {
            const int j = ((e >> 2) << 8) + (lane << 2) + (e & 3);
            const bool valid = mask_type ? (j <= i_row) : (j < i_row);
            const float incl = ((e < 4) ? ex0 : (T0 + ex1)) + c[e];
            const float suffix = disttot - incl;
            const float pos = fabsf((float)(i_row - j));
            const float dist = sqrtf(fmaxf(suffix * pos, 0.f));
            float te = __expf(dist * gneg);
            te = fminf(fmaxf(te, 1e-5f), 1e5f);
            s2[e] = valid ? s[a][e] * te : -1e32f;
            m2 = fmaxf(m2, s2[e]);
        }
#pragma unroll
        for (int o = 32; o; o >>= 1) m2 = fmaxf(m2, __shfl_xor(m2, o));
        float sum2 = 0.f;
#pragma unroll
        for (int e = 0; e < 8; ++e) { s2[e] = __expf(s2[e] - m2); sum2 += s2[e]; }
#pragma unroll
        for (int o = 32; o; o >>= 1) sum2 += __shfl_xor(sum2, o);
        const float rs2 = 1.f / sum2;

        float4 w0, w1;
        w0.x = s2[0] * rs2; w0.y = s2[1] * rs2; w0.z = s2[2] * rs2; w0.w = s2[3] * rs2;
        w1.x = s2[4] * rs2; w1.y = s2[5] * rs2; w1.z = s2[6] * rs2; w1.w = s2[7] * rs2;
        *(float4*)&A[(qg << 2) + a][lane << 2] = w0;
        *(float4*)&A[(qg << 2) + a][256 + (lane << 2)] = w1;
    }
    __syncthreads();

    const int js = t >> 6;
    const int qg2 = (t >> 4) & 3;
    const int dg = t & 15;
    float4 acc[4];
#pragma unroll
    for (int qk = 0; qk < 4; ++qk) acc[qk] = make_float4(0.f, 0.f, 0.f, 0.f);

    const float* vp = Vn + ((size_t)(b * Sdim + js * 128)) * Ddim + h * 64 + (dg << 2);
    for (int jj = 0; jj < 128; jj += 4) {
        float4 aa[4];
#pragma unroll
        for (int qk = 0; qk < 4; ++qk)
            aa[qk] = *(const float4*)&A[(qg2 << 2) + qk][js * 128 + jj];
#pragma unroll
        for (int u = 0; u < 4; ++u) {
            const float4 vv = *(const float4*)(vp + (size_t)(jj + u) * Ddim);
            const float au[4] = {
                u == 0 ? aa[0].x : u == 1 ? aa[0].y : u == 2 ? aa[0].z : aa[0].w,
                u == 0 ? aa[1].x : u == 1 ? aa[1].y : u == 2 ? aa[1].z : aa[1].w,
                u == 0 ? aa[2].x : u == 1 ? aa[2].y : u == 2 ? aa[2].z : aa[2].w,
                u == 0 ? aa[3].x : u == 1 ? aa[3].y : u == 2 ? aa[3].z : aa[3].w };
#pragma unroll
            for (int qk = 0; qk < 4; ++qk) {
                acc[qk].x += au[qk] * vv.x;
                acc[qk].y += au[qk] * vv.y;
                acc[qk].z += au[qk] * vv.z;
                acc[qk].w += au[qk] * vv.w;
            }
        }
    }
#pragma unroll
    for (int qk = 0; qk < 4; ++qk)
        *(float4*)&U[((js * 16) + (qg2 << 2) + qk) * 64 + (dg << 2)] = acc[qk];
    __syncthreads();

    {
        const int q = t >> 4, d4 = (t & 15) << 2;
        float4 r = make_float4(0.f, 0.f, 0.f, 0.f);
#pragma unroll
        for (int j2 = 0; j2 < 4; ++j2) {
            float4 pv = *(const float4*)&U[(j2 * 16 + q) * 64 + d4];
            r.x += pv.x; r.y += pv.y; r.z += pv.z; r.w += pv.w;
        }
        *(float4*)(O + ((size_t)(b * Sdim + qt * 16 + q)) * Ddim + h * 64 + d4) = r;
    }
}

// ---------------------------------------------------------------------------
// LayerNorm over last dim (512) + optional bf16 mirror output.
// ---------------------------------------------------------------------------
__global__ __launch_bounds__(256) void ln_kernel(
    const float* __restrict__ X, const float* __restrict__ g,
    const float* __restrict__ bta, float* __restrict__ Y,
    unsigned short* __restrict__ Yb)
{
    const int row = blockIdx.x;
    const int t = threadIdx.x;
    __shared__ float r1[256], r2[256];
    const float* x = X + (size_t)row * Ddim;
    float a = x[t], b = x[t + 256];
    r1[t] = a + b;
    r2[t] = a * a + b * b;
    __syncthreads();
    for (int off = 128; off; off >>= 1) {
        if (t < off) { r1[t] += r1[t + off]; r2[t] += r2[t + off]; }
        __syncthreads();
    }
    float mean = r1[0] * (1.f / Ddim);
    float var = r2[0] * (1.f / Ddim) - mean * mean;
    float rs = rsqrtf(var + 1e-5f);
    float y0 = (a - mean) * rs * g[t] + bta[t];
    float y1 = (b - mean) * rs * g[t + 256] + bta[t + 256];
    float* y = Y + (size_t)row * Ddim;
    y[t] = y0;
    y[t + 256] = y1;
    if (Yb) {
        unsigned short* yb = Yb + (size_t)row * Ddim;
        yb[t] = f2b(y0);
        yb[t + 256] = f2b(y1);
    }
}

// ---------------------------------------------------------------------------
extern "C" void kernel_launch(void* const* d_in, const int* in_sizes, int n_in,
                              void* d_out, int out_size, void* d_ws, size_t ws_size,
                              hipStream_t stream)
{
    const float* x0     = (const float*)d_in[0];
    const float* y0     = (const float*)d_in[1];
    const float* Wk     = (const float*)d_in[2];
    const float* bk     = (const float*)d_in[3];
    const float* Wv     = (const float*)d_in[4];
    const float* bv     = (const float*)d_in[5];
    const float* Wo     = (const float*)d_in[6];
    const float* bo     = (const float*)d_in[7];
    const float* gammas = (const float*)d_in[8];
    const float* ln1g   = (const float*)d_in[9];
    const float* ln1b   = (const float*)d_in[10];
    const float* W1     = (const float*)d_in[11];
    const float* b1     = (const float*)d_in[12];
    const float* W2     = (const float*)d_in[13];
    const float* b2     = (const float*)d_in[14];
    const float* ln2g   = (const float*)d_in[15];
    const float* ln2b   = (const float*)d_in[16];

    const size_t NBSD = (size_t)Mrows * Ddim;   // 4,194,304
    float* ws = (float*)d_ws;
    // fp32 buffers
    float* Kbuf = ws;               // also T1 (pre-LN) after attention
    float* Vbuf = Kbuf + NBSD;      // also X1 (post-LN1) in FFN blocks
    float* AO   = Vbuf + NBSD;
    float* Ybuf = AO + NBSD;
    float* Xbuf = Ybuf + NBSD;
    // union region: Ktb (fp32, attention) | Abf (bf16 activations, GEMMs)
    float* U8   = Xbuf + NBSD;
    float* Ktb  = U8;
    unsigned short* Abf = (unsigned short*)U8;              // NBSD bf16
    // bf16 buffers
    unsigned short* Hbbf = (unsigned short*)(U8 + NBSD);    // [M,F] bf16 hidden
    unsigned short* Xbf  = Hbbf + (size_t)Mrows * Fdim;
    unsigned short* Ybf  = Xbf + NBSD;
    unsigned short* Wta  = Ybf + NBSD;                      // up to 2048*512
    unsigned short* Wtb  = Wta + (size_t)Fdim * Ddim;
    float* T1 = Kbuf;
    float* X1 = Vbuf;

    const dim3 gDD(Ddim / 128, Mrows / 128);     // (4, 64)
    const dim3 gDF(Fdim / 128, Mrows / 128);     // (16, 64)
    const int convBlocks = (int)(NBSD / 2048);

    auto run_block = [&](int l, const float* qinf, const unsigned short* qinb,
                         const unsigned short* vinb, int mask_type, bool ffn,
                         float* out, unsigned short* outb) {
        const float* Wk_l = Wk + (size_t)l * Ddim * Ddim;
        const float* bk_l = bk + (size_t)l * Ddim;
        const float* Wv_l = Wv + (size_t)l * Ddim * Ddim;
        const float* bv_l = bv + (size_t)l * Ddim;
        const float* Wo_l = Wo + (size_t)l * Ddim * Ddim;
        const float* bo_l = bo + (size_t)l * Ddim;

        // K (=Q) and V projections (bf16 MFMA, fp32 out)
        wtrans<<<dim3(8, 8), 256, 0, stream>>>(Wk_l, Wta, Ddim, Ddim);
        gemm_mfma<<<gDD, 256, 0, stream>>>((const __hip_bfloat16*)qinb,
            (const __hip_bfloat16*)Wta, bk_l, nullptr, Kbuf, nullptr,
            Mrows, Ddim, Ddim, 0);
        wtrans<<<dim3(8, 8), 256, 0, stream>>>(Wv_l, Wtb, Ddim, Ddim);
        gemm_mfma<<<gDD, 256, 0, stream>>>((const __hip_bfloat16*)vinb,
            (const __hip_bfloat16*)Wtb, bv_l, nullptr, Vbuf, nullptr,
            Mrows, Ddim, Ddim, 0);
        // attention (fp32) — Ktb overlays Abf region (activations dead here)
        ktranspose<<<dim3(Sdim / 64, Hdim, Bdim), 256, 0, stream>>>(Kbuf, Ktb);
        attn_fused<<<dim3(Sdim / 16, Hdim, Bdim), 256, 0, stream>>>(
            Kbuf, Ktb, Vbuf, gammas + (size_t)l * Hdim, AO, mask_type);
        // O-projection + residual -> T1; then LN1
        conv_b<<<convBlocks, 256, 0, stream>>>(AO, Abf);
        wtrans<<<dim3(8, 8), 256, 0, stream>>>(Wo_l, Wta, Ddim, Ddim);
        gemm_mfma<<<gDD, 256, 0, stream>>>((const __hip_bfloat16*)Abf,
            (const __hip_bfloat16*)Wta, bo_l, qinf, T1, nullptr,
            Mrows, Ddim, Ddim, 0);
        float* x1f = ffn ? X1 : out;
        unsigned short* x1b = ffn ? Abf : outb;
        ln_kernel<<<Mrows, 256, 0, stream>>>(T1,
            ln1g + (size_t)l * Ddim, ln1b + (size_t)l * Ddim, x1f, x1b);
        if (ffn) {
            const float* W1_l = W1 + (size_t)l * Ddim * Fdim;
            const float* b1_l = b1 + (size_t)l * Fdim;
            const float* W2_l = W2 + (size_t)l * Fdim * Ddim;
            const float* b2_l = b2 + (size_t)l * Ddim;
            // FFN1: relu, bf16-only output (hidden)
            wtrans<<<dim3(32, 8), 256, 0, stream>>>(W1_l, Wtb, Ddim, Fdim);
            gemm_mfma<<<gDF, 256, 0, stream>>>((const __hip_bfloat16*)Abf,
                (const __hip_bfloat16*)Wtb, b1_l, nullptr, nullptr, Hbbf,
                Mrows, Fdim, Ddim, 1);
            // FFN2: + residual X1 -> T1; LN2
            wtrans<<<dim3(8, 32), 256, 0, stream>>>(W2_l, Wta, Fdim, Ddim);
            gemm_mfma<<<gDD, 256, 0, stream>>>((const __hip_bfloat16*)Hbbf,
                (const __hip_bfloat16*)Wta, b2_l, X1, T1, nullptr,
                Mrows, Ddim, Fdim, 0);
            ln_kernel<<<Mrows, 256, 0, stream>>>(T1,
                ln2g + (size_t)l * Ddim, ln2b + (size_t)l * Ddim, out, outb);
        }
    };

    // Block 0: knowledge encoder (y), mask1, FFN -> Ybuf/Ybf
    conv_b<<<convBlocks, 256, 0, stream>>>(y0, Abf);
    run_block(0, y0, Abf, Abf, 1, true, Ybuf, Ybf);
    // Block 1: question encoder (x), mask1, no FFN -> Xbuf/Xbf
    conv_b<<<convBlocks, 256, 0, stream>>>(x0, Abf);
    run_block(1, x0, Abf, Abf, 1, false, Xbuf, Xbf);
    // Block 2: knowledge retriever, q/k=x, v=y, mask0, FFN -> d_out
    run_block(2, Xbuf, Xbf, Ybf, 0, true, (float*)d_out, nullptr);
}